// Round 1
// baseline (916.404 us; speedup 1.0000x reference)
//
#include <hip/hip_runtime.h>
#include <math.h>

#define EPS 0.3f

// Problem constants (from reference): IN=256, H=64, OUT=16, N_LAYERS=2
// N, E derived from in_sizes.

__global__ void zero_f32(float* __restrict__ p, int n) {
    int i = blockIdx.x * blockDim.x + threadIdx.x;
    if (i < n) p[i] = 0.0f;
}

__global__ void deg_count(const int* __restrict__ dst, float* __restrict__ deg, int E) {
    int i = blockIdx.x * blockDim.x + threadIdx.x;
    if (i < E) atomicAdd(&deg[dst[i]], 1.0f);
}

__global__ void deg_finalize(float* __restrict__ d, int N) {
    int i = blockIdx.x * blockDim.x + threadIdx.x;
    if (i < N) d[i] = rsqrtf(fmaxf(d[i], 1.0f));
}

// x[n][j] = relu(sum_k h[n][k] * t1_w[j][k] + t1_b[j]); 4 nodes/block, j = tid&63
__global__ void t1_relu(const float* __restrict__ h, const float* __restrict__ w,
                        const float* __restrict__ b, float* __restrict__ x, int N) {
    __shared__ float lh[4 * 256];
    int nb = blockIdx.x * 4;
    int tid = threadIdx.x;
    #pragma unroll
    for (int i = 0; i < 4; ++i) {
        int fi = i * 256 + tid;                 // 0..1023
        int node = nb + (fi >> 8);
        lh[fi] = (node < N) ? h[(size_t)nb * 256 + fi] : 0.0f;
    }
    __syncthreads();
    int nl = tid >> 6, j = tid & 63;
    int node = nb + nl;
    if (node >= N) return;
    const float4* hr = (const float4*)&lh[nl * 256];
    const float4* wr = (const float4*)&w[j * 256];
    float acc = 0.0f;
    #pragma unroll 8
    for (int k = 0; k < 64; ++k) {
        float4 hv = hr[k], wv = wr[k];
        acc += hv.x * wv.x + hv.y * wv.y + hv.z * wv.z + hv.w * wv.w;
    }
    acc += b[j];
    x[(size_t)node * 64 + j] = fmaxf(acc, 0.0f);
}

// a[n] = x[n] . gw[0:64]  (dst half), b[n] = x[n] . gw[64:128] (src half)
__global__ void gate_dots(const float* __restrict__ x, const float* __restrict__ gw,
                          float* __restrict__ a, float* __restrict__ b, int N) {
    int tid = threadIdx.x;
    int node = blockIdx.x * 4 + (tid >> 6);
    int lane = tid & 63;
    if (node >= N) return;
    float v = x[(size_t)node * 64 + lane];
    float av = v * gw[lane];
    float bv = v * gw[64 + lane];
    #pragma unroll
    for (int off = 32; off > 0; off >>= 1) {
        av += __shfl_down(av, off, 64);
        bv += __shfl_down(bv, off, 64);
    }
    if (lane == 0) { a[node] = av; b[node] = bv; }
}

// dstp[i] = EPS * srcp[i]  (safe in-place)
__global__ void scale_copy(const float* __restrict__ srcp, float* __restrict__ dstp, int n) {
    int i = blockIdx.x * blockDim.x + threadIdx.x;
    if (i < n) dstp[i] = EPS * srcp[i];
}

// one wave per edge; lane = feature index
__global__ void edge_scatter(const int* __restrict__ src, const int* __restrict__ dst,
                             const float* __restrict__ a, const float* __restrict__ b,
                             const float* __restrict__ d, const float* __restrict__ xc,
                             float* __restrict__ xn, const float* __restrict__ gb,
                             int l, int E) {
    int tid = threadIdx.x;
    int e = blockIdx.x * 4 + (tid >> 6);
    if (e >= E) return;
    int lane = tid & 63;
    int s = src[e], t = dst[e];
    float g = tanhf(a[t] + b[s] + gb[l]);
    float coef = g * d[t] * d[s];
    float val = xc[(size_t)s * 64 + lane] * coef;
    atomicAdd(&xn[(size_t)t * 64 + lane], val);
}

// logits = x @ t2_w^T + t2_b, then log_softmax over 16 outputs; thread per node
__global__ void out_logsoftmax(const float* __restrict__ x, const float* __restrict__ w,
                               const float* __restrict__ b, float* __restrict__ out, int N) {
    int n = blockIdx.x * blockDim.x + threadIdx.x;
    if (n >= N) return;
    float xi[64];
    const float4* xr = (const float4*)&x[(size_t)n * 64];
    #pragma unroll
    for (int k = 0; k < 16; ++k) {
        float4 v = xr[k];
        xi[4 * k + 0] = v.x; xi[4 * k + 1] = v.y; xi[4 * k + 2] = v.z; xi[4 * k + 3] = v.w;
    }
    float logits[16];
    float mx = -1e30f;
    #pragma unroll
    for (int j = 0; j < 16; ++j) {
        const float4* wr = (const float4*)&w[j * 64];
        float acc = b[j];
        #pragma unroll
        for (int k = 0; k < 16; ++k) {
            float4 wv = wr[k];
            acc += xi[4 * k + 0] * wv.x + xi[4 * k + 1] * wv.y
                 + xi[4 * k + 2] * wv.z + xi[4 * k + 3] * wv.w;
        }
        logits[j] = acc;
        mx = fmaxf(mx, acc);
    }
    float sum = 0.0f;
    #pragma unroll
    for (int j = 0; j < 16; ++j) sum += expf(logits[j] - mx);
    float lse = mx + logf(sum);
    #pragma unroll
    for (int j = 0; j < 16; ++j) out[(size_t)n * 16 + j] = logits[j] - lse;
}

extern "C" void kernel_launch(void* const* d_in, const int* in_sizes, int n_in,
                              void* d_out, int out_size, void* d_ws, size_t ws_size,
                              hipStream_t stream) {
    const float* h    = (const float*)d_in[0];
    const int*   src  = (const int*)d_in[1];
    const int*   dst  = (const int*)d_in[2];
    const float* t1w  = (const float*)d_in[3];
    const float* t1b  = (const float*)d_in[4];
    const float* gw   = (const float*)d_in[5];   // [2, 128]
    const float* gb   = (const float*)d_in[6];   // [2]
    const float* t2w  = (const float*)d_in[7];   // [16, 64]
    const float* t2b  = (const float*)d_in[8];   // [16]
    float* out = (float*)d_out;

    const int N = in_sizes[0] / 256;
    const int E = in_sizes[1];

    float* XA    = (float*)d_ws;                 // N*64 — x0 (raw) -> becomes x2
    float* XB    = XA + (size_t)N * 64;          // N*64 — x1
    float* dcoef = XB + (size_t)N * 64;          // N    — deg, then rsqrt
    float* ga    = dcoef + N;                    // N    — a (dst-half gate dot)
    float* gbuf  = ga + N;                       // N    — b (src-half gate dot)

    // degree norm
    zero_f32<<<(N + 255) / 256, 256, 0, stream>>>(dcoef, N);
    deg_count<<<(E + 255) / 256, 256, 0, stream>>>(dst, dcoef, E);
    deg_finalize<<<(N + 255) / 256, 256, 0, stream>>>(dcoef, N);

    // x0 = relu(h @ t1_w^T + t1_b)
    t1_relu<<<(N + 3) / 4, 256, 0, stream>>>(h, t1w, t1b, XA, N);

    // layer 0: x_cur = XA (raw), x_next = XB
    gate_dots<<<(N + 3) / 4, 256, 0, stream>>>(XA, gw + 0 * 128, ga, gbuf, N);
    scale_copy<<<(N * 64 + 255) / 256, 256, 0, stream>>>(XA, XB, N * 64);
    edge_scatter<<<(E + 3) / 4, 256, 0, stream>>>(src, dst, ga, gbuf, dcoef, XA, XB, gb, 0, E);

    // layer 1: x_cur = XB, x_next = XA (raw still lives in XA; scale it in place)
    gate_dots<<<(N + 3) / 4, 256, 0, stream>>>(XB, gw + 1 * 128, ga, gbuf, N);
    scale_copy<<<(N * 64 + 255) / 256, 256, 0, stream>>>(XA, XA, N * 64);
    edge_scatter<<<(E + 3) / 4, 256, 0, stream>>>(src, dst, ga, gbuf, dcoef, XB, XA, gb, 1, E);

    // logits + log_softmax
    out_logsoftmax<<<(N + 255) / 256, 256, 0, stream>>>(XA, t2w, t2b, out, N);
}

// Round 2
// 578.063 us; speedup vs baseline: 1.5853x; 1.5853x over previous
//
#include <hip/hip_runtime.h>
#include <math.h>

#define EPS 0.3f

typedef __attribute__((ext_vector_type(8))) short bf16x8;
typedef __attribute__((ext_vector_type(4))) float f32x4;

__device__ __forceinline__ short f2bf(float f) {
    union { float f; unsigned u; } v; v.f = f;
    unsigned r = v.u + 0x7FFFu + ((v.u >> 16) & 1u);  // RNE
    return (short)(r >> 16);
}

__global__ void zero_f32(float* __restrict__ p, int n) {
    int i = blockIdx.x * blockDim.x + threadIdx.x;
    if (i < n) p[i] = 0.0f;
}

__global__ void deg_count(const int* __restrict__ dst, float* __restrict__ deg, int E) {
    int i = blockIdx.x * blockDim.x + threadIdx.x;
    if (i < E) atomicAdd(&deg[dst[i]], 1.0f);
}

__global__ void deg_finalize(float* __restrict__ d, int N) {
    int i = blockIdx.x * blockDim.x + threadIdx.x;
    if (i < N) d[i] = rsqrtf(fmaxf(d[i], 1.0f));
}

// w [64][256] fp32 -> bf16, row-major
__global__ void cvt_w(const float* __restrict__ w, short* __restrict__ wb) {
    int i = blockIdx.x * blockDim.x + threadIdx.x;   // 16384 total
    if (i < 64 * 256) wb[i] = f2bf(w[i]);
}

// x0 = relu(h @ w^T + b); fused: XA=x0, XB=EPS*x0, ga/gb = layer-0 gate dots.
// One wave per 16 nodes. A from global h (fp32->bf16 in-reg), B from bf16 w.
// MFMA 16x16x32 bf16. A: [m=lane&15][k=quad*8+j]; B: [k=quad*8+j][n=lane&15];
// D: col=lane&15, row=quad*4+reg.
__global__ __launch_bounds__(256) void t1_mfma(
    const float* __restrict__ h, const short* __restrict__ wb,
    const float* __restrict__ t1b, const float* __restrict__ gw,
    float* __restrict__ XA, float* __restrict__ XB,
    float* __restrict__ ga, float* __restrict__ gbv, int N)
{
    int wave = threadIdx.x >> 6;
    int lane = threadIdx.x & 63;
    int l15 = lane & 15, quad = lane >> 4;
    int M0 = (blockIdx.x * 4 + wave) * 16;
    if (M0 >= N) return;

    f32x4 acc[4];
    #pragma unroll
    for (int nt = 0; nt < 4; ++nt) acc[nt] = (f32x4){0.f, 0.f, 0.f, 0.f};

    const float* ha = h + (size_t)(M0 + l15) * 256 + quad * 8;
    const short* wq = wb + quad * 8;

    #pragma unroll
    for (int kc = 0; kc < 256; kc += 32) {
        float4 a0 = *(const float4*)(ha + kc);
        float4 a1 = *(const float4*)(ha + kc + 4);
        bf16x8 af;
        af[0] = f2bf(a0.x); af[1] = f2bf(a0.y); af[2] = f2bf(a0.z); af[3] = f2bf(a0.w);
        af[4] = f2bf(a1.x); af[5] = f2bf(a1.y); af[6] = f2bf(a1.z); af[7] = f2bf(a1.w);
        #pragma unroll
        for (int nt = 0; nt < 4; ++nt) {
            bf16x8 bf = *(const bf16x8*)(wq + (size_t)(nt * 16 + l15) * 256 + kc);
            acc[nt] = __builtin_amdgcn_mfma_f32_16x16x32_bf16(af, bf, acc[nt], 0, 0, 0);
        }
    }

    float pa[4] = {0.f, 0.f, 0.f, 0.f};
    float pb[4] = {0.f, 0.f, 0.f, 0.f};
    #pragma unroll
    for (int nt = 0; nt < 4; ++nt) {
        int n = nt * 16 + l15;
        float bias = t1b[n];
        float gd = gw[n], gs = gw[64 + n];
        #pragma unroll
        for (int r = 0; r < 4; ++r) {
            float x = fmaxf(acc[nt][r] + bias, 0.f);
            size_t o = (size_t)(M0 + quad * 4 + r) * 64 + n;
            XA[o] = x;
            XB[o] = EPS * x;
            pa[r] += x * gd;
            pb[r] += x * gs;
        }
    }
    #pragma unroll
    for (int off = 1; off < 16; off <<= 1) {
        #pragma unroll
        for (int r = 0; r < 4; ++r) {
            pa[r] += __shfl_xor(pa[r], off, 64);
            pb[r] += __shfl_xor(pb[r], off, 64);
        }
    }
    if (l15 == 0) {
        #pragma unroll
        for (int r = 0; r < 4; ++r) {
            int m = M0 + quad * 4 + r;
            ga[m] = pa[r];
            gbv[m] = pb[r];
        }
    }
}

// layer-1 gate dots from x1, plus raw = EPS*raw in place (prep for scatter)
__global__ void gate_scale(const float* __restrict__ x1, const float* __restrict__ gw,
                           float* __restrict__ raw, float* __restrict__ a,
                           float* __restrict__ b, int N) {
    int tid = threadIdx.x;
    int node = blockIdx.x * 4 + (tid >> 6);
    int lane = tid & 63;
    if (node >= N) return;
    size_t o = (size_t)node * 64 + lane;
    float v = x1[o];
    float rv = raw[o];
    raw[o] = EPS * rv;
    float av = v * gw[lane];
    float bv = v * gw[64 + lane];
    #pragma unroll
    for (int off = 32; off > 0; off >>= 1) {
        av += __shfl_down(av, off, 64);
        bv += __shfl_down(bv, off, 64);
    }
    if (lane == 0) { a[node] = av; b[node] = bv; }
}

// one wave per edge; lane = feature index
__global__ void edge_scatter(const int* __restrict__ src, const int* __restrict__ dst,
                             const float* __restrict__ a, const float* __restrict__ b,
                             const float* __restrict__ d, const float* __restrict__ xc,
                             float* __restrict__ xn, const float* __restrict__ gb,
                             int l, int E) {
    int tid = threadIdx.x;
    int e = blockIdx.x * 4 + (tid >> 6);
    if (e >= E) return;
    int lane = tid & 63;
    int s = src[e], t = dst[e];
    float g = tanhf(a[t] + b[s] + gb[l]);
    float coef = g * d[t] * d[s];
    float val = xc[(size_t)s * 64 + lane] * coef;
    atomicAdd(&xn[(size_t)t * 64 + lane], val);
}

// logits = x @ t2_w^T + t2_b, then log_softmax over 16; thread per node
__global__ void out_logsoftmax(const float* __restrict__ x, const float* __restrict__ w,
                               const float* __restrict__ b, float* __restrict__ out, int N) {
    int n = blockIdx.x * blockDim.x + threadIdx.x;
    if (n >= N) return;
    float xi[64];
    const float4* xr = (const float4*)&x[(size_t)n * 64];
    #pragma unroll
    for (int k = 0; k < 16; ++k) {
        float4 v = xr[k];
        xi[4 * k + 0] = v.x; xi[4 * k + 1] = v.y; xi[4 * k + 2] = v.z; xi[4 * k + 3] = v.w;
    }
    float logits[16];
    float mx = -1e30f;
    #pragma unroll
    for (int j = 0; j < 16; ++j) {
        const float4* wr = (const float4*)&w[j * 64];
        float acc = b[j];
        #pragma unroll
        for (int k = 0; k < 16; ++k) {
            float4 wv = wr[k];
            acc += xi[4 * k + 0] * wv.x + xi[4 * k + 1] * wv.y
                 + xi[4 * k + 2] * wv.z + xi[4 * k + 3] * wv.w;
        }
        logits[j] = acc;
        mx = fmaxf(mx, acc);
    }
    float sum = 0.0f;
    #pragma unroll
    for (int j = 0; j < 16; ++j) sum += expf(logits[j] - mx);
    float lse = mx + logf(sum);
    #pragma unroll
    for (int j = 0; j < 16; ++j) out[(size_t)n * 16 + j] = logits[j] - lse;
}

extern "C" void kernel_launch(void* const* d_in, const int* in_sizes, int n_in,
                              void* d_out, int out_size, void* d_ws, size_t ws_size,
                              hipStream_t stream) {
    const float* h    = (const float*)d_in[0];
    const int*   src  = (const int*)d_in[1];
    const int*   dst  = (const int*)d_in[2];
    const float* t1w  = (const float*)d_in[3];
    const float* t1b  = (const float*)d_in[4];
    const float* gw   = (const float*)d_in[5];   // [2, 128]
    const float* gbia = (const float*)d_in[6];   // [2]
    const float* t2w  = (const float*)d_in[7];   // [16, 64]
    const float* t2b  = (const float*)d_in[8];   // [16]
    float* out = (float*)d_out;

    const int N = in_sizes[0] / 256;
    const int E = in_sizes[1];

    float* XA    = (float*)d_ws;                 // N*64 — x0 (raw), becomes x2
    float* XB    = XA + (size_t)N * 64;          // N*64 — EPS*x0, becomes x1
    float* dcoef = XB + (size_t)N * 64;          // N
    float* ga    = dcoef + N;                    // N
    float* gb    = ga + N;                       // N
    size_t off   = ((size_t)N * (128 + 3) * 4 + 63) & ~(size_t)63;
    short* wbf   = (short*)((char*)d_ws + off);  // 64*256 bf16 weights

    // degree norm
    zero_f32<<<(N + 255) / 256, 256, 0, stream>>>(dcoef, N);
    deg_count<<<(E + 255) / 256, 256, 0, stream>>>(dst, dcoef, E);
    deg_finalize<<<(N + 255) / 256, 256, 0, stream>>>(dcoef, N);

    // w -> bf16
    cvt_w<<<64, 256, 0, stream>>>(t1w, wbf);

    // x0 = relu(h@w^T+b); XA=x0, XB=EPS*x0, ga/gb = layer-0 gate dots
    t1_mfma<<<(N + 63) / 64, 256, 0, stream>>>(h, wbf, t1b, gw, XA, XB, ga, gb, N);

    // layer 0: gather XA (x0), accumulate into XB (pre-seeded EPS*x0) -> x1
    edge_scatter<<<(E + 3) / 4, 256, 0, stream>>>(src, dst, ga, gb, dcoef, XA, XB, gbia, 0, E);

    // layer 1 prep: gate dots from x1 (XB); XA = EPS*raw in place
    gate_scale<<<(N + 3) / 4, 256, 0, stream>>>(XB, gw + 128, XA, ga, gb, N);

    // layer 1: gather XB (x1), accumulate into XA -> x2
    edge_scatter<<<(E + 3) / 4, 256, 0, stream>>>(src, dst, ga, gb, dcoef, XB, XA, gbia, 1, E);

    // logits + log_softmax
    out_logsoftmax<<<(N + 255) / 256, 256, 0, stream>>>(XA, t2w, t2b, out, N);
}

// Round 3
// 446.146 us; speedup vs baseline: 2.0540x; 1.2957x over previous
//
#include <hip/hip_runtime.h>
#include <math.h>

#define EPS 0.3f

typedef __attribute__((ext_vector_type(8))) short bf16x8;
typedef __attribute__((ext_vector_type(4))) float f32x4;

__device__ __forceinline__ short f2bf(float f) {
    union { float f; unsigned u; } v; v.f = f;
    unsigned r = v.u + 0x7FFFu + ((v.u >> 16) & 1u);  // RNE
    return (short)(r >> 16);
}

__global__ void zero_i32(int* __restrict__ p, int n) {
    int i = blockIdx.x * blockDim.x + threadIdx.x;
    if (i < n) p[i] = 0;
}

__global__ void deg_count_i(const int* __restrict__ dst, int* __restrict__ cnt, int E) {
    int i = blockIdx.x * blockDim.x + threadIdx.x;
    if (i < E) atomicAdd(&cnt[dst[i]], 1);
}

__global__ void deg_finalize(const int* __restrict__ cnt, float* __restrict__ d, int N) {
    int i = blockIdx.x * blockDim.x + threadIdx.x;
    if (i < N) d[i] = rsqrtf(fmaxf((float)cnt[i], 1.0f));
}

// per-block exclusive scan of cnt -> rs; block totals -> bsum
__global__ void scan_block(const int* __restrict__ cnt, int* __restrict__ rs,
                           int* __restrict__ bsum, int N) {
    __shared__ int tmp[256];
    int tid = threadIdx.x;
    int i = blockIdx.x * 256 + tid;
    int v = (i < N) ? cnt[i] : 0;
    tmp[tid] = v;
    __syncthreads();
    #pragma unroll
    for (int off = 1; off < 256; off <<= 1) {
        int other = (tid >= off) ? tmp[tid - off] : 0;
        __syncthreads();
        tmp[tid] += other;
        __syncthreads();
    }
    if (i < N) rs[i] = tmp[tid] - v;          // exclusive
    if (tid == 255) bsum[blockIdx.x] = tmp[tid];
}

// single-block exclusive scan of bsum (nb <= 1024), in place
__global__ void scan_top(int* __restrict__ bsum, int nb) {
    __shared__ int tmp[1024];
    int tid = threadIdx.x;
    int v = (tid < nb) ? bsum[tid] : 0;
    tmp[tid] = v;
    __syncthreads();
    #pragma unroll
    for (int off = 1; off < 1024; off <<= 1) {
        int other = (tid >= off) ? tmp[tid - off] : 0;
        __syncthreads();
        tmp[tid] += other;
        __syncthreads();
    }
    if (tid < nb) bsum[tid] = tmp[tid] - v;   // exclusive
}

// rs[i] += bsum[block]; cursor copy; rs[N] = E
__global__ void scan_add(int* __restrict__ rs, const int* __restrict__ bsum,
                         int* __restrict__ cur, int N, int E) {
    int i = blockIdx.x * 256 + threadIdx.x;
    if (i < N) {
        int v = rs[i] + bsum[blockIdx.x];
        rs[i] = v;
        cur[i] = v;
    }
    if (i == 0) rs[N] = E;
}

__global__ void bucket_fill(const int* __restrict__ src, const int* __restrict__ dst,
                            int* __restrict__ cur, int* __restrict__ esrc, int E) {
    int i = blockIdx.x * blockDim.x + threadIdx.x;
    if (i < E) {
        int p = atomicAdd(&cur[dst[i]], 1);
        esrc[p] = src[i];
    }
}

// w [64][256] fp32 -> bf16
__global__ void cvt_w(const float* __restrict__ w, short* __restrict__ wb) {
    int i = blockIdx.x * blockDim.x + threadIdx.x;
    if (i < 64 * 256) wb[i] = f2bf(w[i]);
}

// x0 = relu(h @ w^T + b); fused layer-0 gate dots.
// MFMA 16x16x32 bf16. A: [m=lane&15][k=quad*8+j]; D: col=lane&15, row=quad*4+reg.
__global__ __launch_bounds__(256) void t1_mfma(
    const float* __restrict__ h, const short* __restrict__ wb,
    const float* __restrict__ t1b, const float* __restrict__ gw,
    float* __restrict__ XA, float* __restrict__ ga, float* __restrict__ gbv, int N)
{
    int wave = threadIdx.x >> 6;
    int lane = threadIdx.x & 63;
    int l15 = lane & 15, quad = lane >> 4;
    int M0 = (blockIdx.x * 4 + wave) * 16;
    if (M0 >= N) return;

    f32x4 acc[4];
    #pragma unroll
    for (int nt = 0; nt < 4; ++nt) acc[nt] = (f32x4){0.f, 0.f, 0.f, 0.f};

    const float* ha = h + (size_t)(M0 + l15) * 256 + quad * 8;
    const short* wq = wb + quad * 8;

    #pragma unroll
    for (int kc = 0; kc < 256; kc += 32) {
        float4 a0 = *(const float4*)(ha + kc);
        float4 a1 = *(const float4*)(ha + kc + 4);
        bf16x8 af;
        af[0] = f2bf(a0.x); af[1] = f2bf(a0.y); af[2] = f2bf(a0.z); af[3] = f2bf(a0.w);
        af[4] = f2bf(a1.x); af[5] = f2bf(a1.y); af[6] = f2bf(a1.z); af[7] = f2bf(a1.w);
        #pragma unroll
        for (int nt = 0; nt < 4; ++nt) {
            bf16x8 bf = *(const bf16x8*)(wq + (size_t)(nt * 16 + l15) * 256 + kc);
            acc[nt] = __builtin_amdgcn_mfma_f32_16x16x32_bf16(af, bf, acc[nt], 0, 0, 0);
        }
    }

    float pa[4] = {0.f, 0.f, 0.f, 0.f};
    float pb[4] = {0.f, 0.f, 0.f, 0.f};
    #pragma unroll
    for (int nt = 0; nt < 4; ++nt) {
        int n = nt * 16 + l15;
        float bias = t1b[n];
        float gd = gw[n], gs = gw[64 + n];
        #pragma unroll
        for (int r = 0; r < 4; ++r) {
            float x = fmaxf(acc[nt][r] + bias, 0.f);
            XA[(size_t)(M0 + quad * 4 + r) * 64 + n] = x;
            pa[r] += x * gd;
            pb[r] += x * gs;
        }
    }
    #pragma unroll
    for (int off = 1; off < 16; off <<= 1) {
        #pragma unroll
        for (int r = 0; r < 4; ++r) {
            pa[r] += __shfl_xor(pa[r], off, 64);
            pb[r] += __shfl_xor(pb[r], off, 64);
        }
    }
    if (l15 == 0) {
        #pragma unroll
        for (int r = 0; r < 4; ++r) {
            int m = M0 + quad * 4 + r;
            ga[m] = pa[r];
            gbv[m] = pb[r];
        }
    }
}

// One wave per dst node: x_next[t] = EPS*raw[t] + sum_e coef(e) * x_cur[src(e)].
// Optionally fuses next layer's gate dots from the freshly computed row.
__global__ __launch_bounds__(256) void gather(
    const int* __restrict__ rs, const int* __restrict__ esrc,
    const float* __restrict__ a, const float* __restrict__ b,
    const float* __restrict__ d, const float* __restrict__ xc,
    const float* __restrict__ raw, float* __restrict__ xn,
    const float* __restrict__ gw_next, float* __restrict__ ga_next,
    float* __restrict__ gb_next, const float* __restrict__ gbp, int layer, int N)
{
    int tid = threadIdx.x;
    int t = blockIdx.x * 4 + (tid >> 6);
    if (t >= N) return;
    int lane = tid & 63;
    float gbias = gbp[layer];
    int beg = rs[t], end = rs[t + 1];
    float at = a[t], dt = d[t];
    float acc = EPS * raw[(size_t)t * 64 + lane];

    int i = beg;
    if (i < end) {
        int s = esrc[i];
        while (true) {
            int snext = (i + 1 < end) ? esrc[i + 1] : 0;
            float coef = tanhf(at + b[s] + gbias) * dt * d[s];
            acc += xc[(size_t)s * 64 + lane] * coef;
            ++i;
            if (i >= end) break;
            s = snext;
        }
    }
    xn[(size_t)t * 64 + lane] = acc;

    if (gw_next) {
        float av = acc * gw_next[lane];
        float bv = acc * gw_next[64 + lane];
        #pragma unroll
        for (int off = 32; off > 0; off >>= 1) {
            av += __shfl_down(av, off, 64);
            bv += __shfl_down(bv, off, 64);
        }
        if (lane == 0) { ga_next[t] = av; gb_next[t] = bv; }
    }
}

// logits = x @ t2_w^T + t2_b, then log_softmax over 16; thread per node
__global__ void out_logsoftmax(const float* __restrict__ x, const float* __restrict__ w,
                               const float* __restrict__ b, float* __restrict__ out, int N) {
    int n = blockIdx.x * blockDim.x + threadIdx.x;
    if (n >= N) return;
    float xi[64];
    const float4* xr = (const float4*)&x[(size_t)n * 64];
    #pragma unroll
    for (int k = 0; k < 16; ++k) {
        float4 v = xr[k];
        xi[4 * k + 0] = v.x; xi[4 * k + 1] = v.y; xi[4 * k + 2] = v.z; xi[4 * k + 3] = v.w;
    }
    float logits[16];
    float mx = -1e30f;
    #pragma unroll
    for (int j = 0; j < 16; ++j) {
        const float4* wr = (const float4*)&w[j * 64];
        float acc = b[j];
        #pragma unroll
        for (int k = 0; k < 16; ++k) {
            float4 wv = wr[k];
            acc += xi[4 * k + 0] * wv.x + xi[4 * k + 1] * wv.y
                 + xi[4 * k + 2] * wv.z + xi[4 * k + 3] * wv.w;
        }
        logits[j] = acc;
        mx = fmaxf(mx, acc);
    }
    float sum = 0.0f;
    #pragma unroll
    for (int j = 0; j < 16; ++j) sum += expf(logits[j] - mx);
    float lse = mx + logf(sum);
    #pragma unroll
    for (int j = 0; j < 16; ++j) out[(size_t)n * 16 + j] = logits[j] - lse;
}

extern "C" void kernel_launch(void* const* d_in, const int* in_sizes, int n_in,
                              void* d_out, int out_size, void* d_ws, size_t ws_size,
                              hipStream_t stream) {
    const float* h    = (const float*)d_in[0];
    const int*   src  = (const int*)d_in[1];
    const int*   dst  = (const int*)d_in[2];
    const float* t1w  = (const float*)d_in[3];
    const float* t1b  = (const float*)d_in[4];
    const float* gw   = (const float*)d_in[5];   // [2, 128]
    const float* gbia = (const float*)d_in[6];   // [2]
    const float* t2w  = (const float*)d_in[7];   // [16, 64]
    const float* t2b  = (const float*)d_in[8];   // [16]
    float* out = (float*)d_out;

    const int N = in_sizes[0] / 256;
    const int E = in_sizes[1];
    const int NB = (N + 255) / 256;              // scan blocks (<=1024)

    char* p = (char*)d_ws;
    float* XA   = (float*)p;            p += (size_t)N * 64 * 4;   // x0 (raw) -> x2
    float* XB   = (float*)p;            p += (size_t)N * 64 * 4;   // x1
    float* dco  = (float*)p;            p += (size_t)N * 4;
    float* ga0  = (float*)p;            p += (size_t)N * 4;
    float* gb0  = (float*)p;            p += (size_t)N * 4;
    float* ga1  = (float*)p;            p += (size_t)N * 4;
    float* gb1  = (float*)p;            p += (size_t)N * 4;
    int*   cnt  = (int*)p;              p += (size_t)N * 4;
    int*   rs   = (int*)p;              p += (size_t)(N + 1) * 4;
    int*   cur  = (int*)p;              p += (size_t)N * 4;
    int*   bsum = (int*)p;              p += 1024 * 4;
    int*   esrc = (int*)p;              p += (size_t)E * 4;
    short* wbf  = (short*)p;

    // ---- CSR build (counting sort by dst) + degree norm ----
    zero_i32<<<NB, 256, 0, stream>>>(cnt, N);
    deg_count_i<<<(E + 255) / 256, 256, 0, stream>>>(dst, cnt, E);
    deg_finalize<<<NB, 256, 0, stream>>>(cnt, dco, N);
    scan_block<<<NB, 256, 0, stream>>>(cnt, rs, bsum, N);
    scan_top<<<1, 1024, 0, stream>>>(bsum, NB);
    scan_add<<<NB, 256, 0, stream>>>(rs, bsum, cur, N, E);
    bucket_fill<<<(E + 255) / 256, 256, 0, stream>>>(src, dst, cur, esrc, E);

    // ---- t1 + relu (MFMA) with fused layer-0 gate dots ----
    cvt_w<<<64, 256, 0, stream>>>(t1w, wbf);
    t1_mfma<<<(N + 63) / 64, 256, 0, stream>>>(h, wbf, t1b, gw, XA, ga0, gb0, N);

    // ---- layer 0: x1 = EPS*x0 + gather(x0); fused layer-1 gate dots ----
    gather<<<(N + 3) / 4, 256, 0, stream>>>(rs, esrc, ga0, gb0, dco, XA, XA, XB,
                                            gw + 128, ga1, gb1, gbia, 0, N);

    // ---- layer 1: x2 = EPS*x0 + gather(x1) ----
    gather<<<(N + 3) / 4, 256, 0, stream>>>(rs, esrc, ga1, gb1, dco, XB, XA, XA,
                                            nullptr, nullptr, nullptr, gbia, 1, N);

    // ---- logits + log_softmax ----
    out_logsoftmax<<<(N + 255) / 256, 256, 0, stream>>>(XA, t2w, t2b, out, N);
}

// Round 4
// 315.760 us; speedup vs baseline: 2.9022x; 1.4129x over previous
//
#include <hip/hip_runtime.h>
#include <math.h>

#define EPS 0.3f

typedef __attribute__((ext_vector_type(8))) short bf16x8;
typedef __attribute__((ext_vector_type(4))) short bf16x4;
typedef __attribute__((ext_vector_type(4))) float f32x4;

__device__ __forceinline__ short f2bf(float f) {
    union { float f; unsigned u; } v; v.f = f;
    unsigned r = v.u + 0x7FFFu + ((v.u >> 16) & 1u);  // RNE
    return (short)(r >> 16);
}

__global__ void zero_i32(int* __restrict__ p, int n) {
    int i = blockIdx.x * blockDim.x + threadIdx.x;
    if (i < n) p[i] = 0;
}

__global__ void deg_count_i(const int* __restrict__ dst, int* __restrict__ cnt, int E) {
    int i = blockIdx.x * blockDim.x + threadIdx.x;
    if (i < E) atomicAdd(&cnt[dst[i]], 1);
}

__global__ void deg_finalize(const int* __restrict__ cnt, float* __restrict__ d, int N) {
    int i = blockIdx.x * blockDim.x + threadIdx.x;
    if (i < N) d[i] = rsqrtf(fmaxf((float)cnt[i], 1.0f));
}

// per-block exclusive scan of cnt -> rs; block totals -> bsum
__global__ void scan_block(const int* __restrict__ cnt, int* __restrict__ rs,
                           int* __restrict__ bsum, int N) {
    __shared__ int tmp[256];
    int tid = threadIdx.x;
    int i = blockIdx.x * 256 + tid;
    int v = (i < N) ? cnt[i] : 0;
    tmp[tid] = v;
    __syncthreads();
    #pragma unroll
    for (int off = 1; off < 256; off <<= 1) {
        int other = (tid >= off) ? tmp[tid - off] : 0;
        __syncthreads();
        tmp[tid] += other;
        __syncthreads();
    }
    if (i < N) rs[i] = tmp[tid] - v;          // exclusive
    if (tid == 255) bsum[blockIdx.x] = tmp[tid];
}

// single-block exclusive scan of bsum (nb <= 1024), in place
__global__ void scan_top(int* __restrict__ bsum, int nb) {
    __shared__ int tmp[1024];
    int tid = threadIdx.x;
    int v = (tid < nb) ? bsum[tid] : 0;
    tmp[tid] = v;
    __syncthreads();
    #pragma unroll
    for (int off = 1; off < 1024; off <<= 1) {
        int other = (tid >= off) ? tmp[tid - off] : 0;
        __syncthreads();
        tmp[tid] += other;
        __syncthreads();
    }
    if (tid < nb) bsum[tid] = tmp[tid] - v;   // exclusive
}

// rs[i] += bsum[block]; cursor copy; rs[N] = E
__global__ void scan_add(int* __restrict__ rs, const int* __restrict__ bsum,
                         int* __restrict__ cur, int N, int E) {
    int i = blockIdx.x * 256 + threadIdx.x;
    if (i < N) {
        int v = rs[i] + bsum[blockIdx.x];
        rs[i] = v;
        cur[i] = v;
    }
    if (i == 0) rs[N] = E;
}

// counting-sort bucket fill; stores src and dst per CSR slot
__global__ void bucket_fill(const int* __restrict__ src, const int* __restrict__ dst,
                            int* __restrict__ cur, int* __restrict__ esrc,
                            int* __restrict__ edst, int E) {
    int i = blockIdx.x * blockDim.x + threadIdx.x;
    if (i < E) {
        int t = dst[i];
        int p = atomicAdd(&cur[t], 1);
        esrc[p] = src[i];
        edst[p] = t;
    }
}

// w [64][256] fp32 -> bf16
__global__ void cvt_w(const float* __restrict__ w, short* __restrict__ wb) {
    int i = blockIdx.x * blockDim.x + threadIdx.x;
    if (i < 64 * 256) wb[i] = f2bf(w[i]);
}

// per-CSR-slot gate coefficient: tanh(a[t]+b[s]+gb)*d[t]*d[s]
__global__ void edge_coef(const int* __restrict__ esrc, const int* __restrict__ edst,
                          const float* __restrict__ a, const float* __restrict__ b,
                          const float* __restrict__ d, const float* __restrict__ gbp,
                          int layer, float* __restrict__ ecoef, int E) {
    int i = blockIdx.x * blockDim.x + threadIdx.x;
    if (i < E) {
        int s = esrc[i], t = edst[i];
        ecoef[i] = tanhf(a[t] + b[s] + gbp[layer]) * d[t] * d[s];
    }
}

// x0 = relu(h @ w^T + b); fused layer-0 gate dots. LDS-staged A (coalesced).
// MFMA 16x16x32 bf16. A: [m=lane&15][k=quad*8+j]; D: col=lane&15, row=quad*4+reg.
#define LROW 264   // LDS row stride in shorts (256 + 8 pad): 528 B, 16B-aligned
__global__ __launch_bounds__(256) void t1_mfma(
    const float* __restrict__ h, const short* __restrict__ wb,
    const float* __restrict__ t1b, const float* __restrict__ gw,
    float* __restrict__ XA, float* __restrict__ ga, float* __restrict__ gbv, int N)
{
    __shared__ short lh[4][16 * LROW];
    int wave = threadIdx.x >> 6;
    int lane = threadIdx.x & 63;
    int l15 = lane & 15, quad = lane >> 4;
    int M0 = (blockIdx.x * 4 + wave) * 16;
    if (M0 >= N) return;
    int rlim = N - M0;                         // rows valid in this tile (<=16)

    short* myl = lh[wave];
    const float* hb = h + (size_t)M0 * 256;
    #pragma unroll
    for (int r = 0; r < 16; ++r) {
        if (r < rlim) {
            float4 v = *(const float4*)&hb[(size_t)r * 256 + lane * 4];
            bf16x4 sv;
            sv[0] = f2bf(v.x); sv[1] = f2bf(v.y); sv[2] = f2bf(v.z); sv[3] = f2bf(v.w);
            *(bf16x4*)&myl[r * LROW + lane * 4] = sv;
        }
    }
    // same-wave LDS RAW: compiler inserts waitcnt; no barrier needed.

    f32x4 acc[4];
    #pragma unroll
    for (int nt = 0; nt < 4; ++nt) acc[nt] = (f32x4){0.f, 0.f, 0.f, 0.f};

    const short* wq = wb + quad * 8;
    #pragma unroll
    for (int kc = 0; kc < 256; kc += 32) {
        bf16x8 af = *(const bf16x8*)&myl[l15 * LROW + kc + quad * 8];
        #pragma unroll
        for (int nt = 0; nt < 4; ++nt) {
            bf16x8 bf = *(const bf16x8*)(wq + (size_t)(nt * 16 + l15) * 256 + kc);
            acc[nt] = __builtin_amdgcn_mfma_f32_16x16x32_bf16(af, bf, acc[nt], 0, 0, 0);
        }
    }

    float pa[4] = {0.f, 0.f, 0.f, 0.f};
    float pb[4] = {0.f, 0.f, 0.f, 0.f};
    #pragma unroll
    for (int nt = 0; nt < 4; ++nt) {
        int n = nt * 16 + l15;
        float bias = t1b[n];
        float gd = gw[n], gs = gw[64 + n];
        #pragma unroll
        for (int r = 0; r < 4; ++r) {
            int row = quad * 4 + r;
            if (row < rlim) {
                float x = fmaxf(acc[nt][r] + bias, 0.f);
                XA[(size_t)(M0 + row) * 64 + n] = x;
                pa[r] += x * gd;
                pb[r] += x * gs;
            }
        }
    }
    #pragma unroll
    for (int off = 1; off < 16; off <<= 1) {
        #pragma unroll
        for (int r = 0; r < 4; ++r) {
            pa[r] += __shfl_xor(pa[r], off, 64);
            pb[r] += __shfl_xor(pb[r], off, 64);
        }
    }
    if (l15 == 0) {
        #pragma unroll
        for (int r = 0; r < 4; ++r) {
            int row = quad * 4 + r;
            if (row < rlim) {
                ga[M0 + row] = pa[r];
                gbv[M0 + row] = pb[r];
            }
        }
    }
}

// One wave per dst node, 4 edge-groups x 16 feature-quads (float4/lane):
// x_next[t] = EPS*raw[t] + sum_e ecoef[e] * x_cur[src(e)].
// Optionally fuses next layer's gate dots from the freshly computed row.
__global__ __launch_bounds__(256) void gather4(
    const int* __restrict__ rs, const int* __restrict__ esrc,
    const float* __restrict__ ecoef, const float* __restrict__ xc,
    const float* __restrict__ raw, float* __restrict__ xn,
    const float* __restrict__ gw_next, float* __restrict__ ga_next,
    float* __restrict__ gb_next, int N)
{
    int tid = threadIdx.x;
    int t = blockIdx.x * 4 + (tid >> 6);
    if (t >= N) return;
    int lane = tid & 63;
    int g = lane >> 4;        // edge group 0..3
    int q = lane & 15;        // feature quad; features 4q..4q+3
    int beg = rs[t], end = rs[t + 1];

    float ax = 0.f, ay = 0.f, az = 0.f, aw = 0.f;
    if (g == 0) {
        float4 rv = *(const float4*)&raw[(size_t)t * 64 + q * 4];
        ax = EPS * rv.x; ay = EPS * rv.y; az = EPS * rv.z; aw = EPS * rv.w;
    }

    int i = beg + g;
    // 2x unrolled: two independent edges in flight per group
    for (; i + 4 < end; i += 8) {
        int s0 = esrc[i];
        int s1 = esrc[i + 4];
        float c0 = ecoef[i];
        float c1 = ecoef[i + 4];
        float4 x0 = *(const float4*)&xc[(size_t)s0 * 64 + q * 4];
        float4 x1 = *(const float4*)&xc[(size_t)s1 * 64 + q * 4];
        ax += c0 * x0.x + c1 * x1.x;
        ay += c0 * x0.y + c1 * x1.y;
        az += c0 * x0.z + c1 * x1.z;
        aw += c0 * x0.w + c1 * x1.w;
    }
    if (i < end) {
        int s0 = esrc[i];
        float c0 = ecoef[i];
        float4 x0 = *(const float4*)&xc[(size_t)s0 * 64 + q * 4];
        ax += c0 * x0.x; ay += c0 * x0.y; az += c0 * x0.z; aw += c0 * x0.w;
    }

    // reduce across the 4 edge groups (lanes differing in bits 4,5)
    #pragma unroll
    for (int off = 16; off < 64; off <<= 1) {
        ax += __shfl_xor(ax, off, 64);
        ay += __shfl_xor(ay, off, 64);
        az += __shfl_xor(az, off, 64);
        aw += __shfl_xor(aw, off, 64);
    }
    if (g == 0) {
        float4 o; o.x = ax; o.y = ay; o.z = az; o.w = aw;
        *(float4*)&xn[(size_t)t * 64 + q * 4] = o;
    }

    if (gw_next) {
        float4 gd = *(const float4*)&gw_next[q * 4];
        float4 gs = *(const float4*)&gw_next[64 + q * 4];
        float av = ax * gd.x + ay * gd.y + az * gd.z + aw * gd.w;
        float bv = ax * gs.x + ay * gs.y + az * gs.z + aw * gs.w;
        #pragma unroll
        for (int off = 1; off < 16; off <<= 1) {
            av += __shfl_xor(av, off, 64);
            bv += __shfl_xor(bv, off, 64);
        }
        if (lane == 0) { ga_next[t] = av; gb_next[t] = bv; }
    }
}

// logits = x @ t2_w^T + t2_b, then log_softmax over 16; thread per node
__global__ void out_logsoftmax(const float* __restrict__ x, const float* __restrict__ w,
                               const float* __restrict__ b, float* __restrict__ out, int N) {
    int n = blockIdx.x * blockDim.x + threadIdx.x;
    if (n >= N) return;
    float xi[64];
    const float4* xr = (const float4*)&x[(size_t)n * 64];
    #pragma unroll
    for (int k = 0; k < 16; ++k) {
        float4 v = xr[k];
        xi[4 * k + 0] = v.x; xi[4 * k + 1] = v.y; xi[4 * k + 2] = v.z; xi[4 * k + 3] = v.w;
    }
    float logits[16];
    float mx = -1e30f;
    #pragma unroll
    for (int j = 0; j < 16; ++j) {
        const float4* wr = (const float4*)&w[j * 64];
        float acc = b[j];
        #pragma unroll
        for (int k = 0; k < 16; ++k) {
            float4 wv = wr[k];
            acc += xi[4 * k + 0] * wv.x + xi[4 * k + 1] * wv.y
                 + xi[4 * k + 2] * wv.z + xi[4 * k + 3] * wv.w;
        }
        logits[j] = acc;
        mx = fmaxf(mx, acc);
    }
    float sum = 0.0f;
    #pragma unroll
    for (int j = 0; j < 16; ++j) sum += expf(logits[j] - mx);
    float lse = mx + logf(sum);
    #pragma unroll
    for (int j = 0; j < 16; ++j) out[(size_t)n * 16 + j] = logits[j] - lse;
}

extern "C" void kernel_launch(void* const* d_in, const int* in_sizes, int n_in,
                              void* d_out, int out_size, void* d_ws, size_t ws_size,
                              hipStream_t stream) {
    const float* h    = (const float*)d_in[0];
    const int*   src  = (const int*)d_in[1];
    const int*   dst  = (const int*)d_in[2];
    const float* t1w  = (const float*)d_in[3];
    const float* t1b  = (const float*)d_in[4];
    const float* gw   = (const float*)d_in[5];   // [2, 128]
    const float* gbia = (const float*)d_in[6];   // [2]
    const float* t2w  = (const float*)d_in[7];   // [16, 64]
    const float* t2b  = (const float*)d_in[8];   // [16]
    float* out = (float*)d_out;

    const int N = in_sizes[0] / 256;
    const int E = in_sizes[1];
    const int NB = (N + 255) / 256;              // scan blocks (<=1024)

    char* p = (char*)d_ws;
    float* XA    = (float*)p;           p += (size_t)N * 64 * 4;   // x0 (raw) -> x2
    float* XB    = (float*)p;           p += (size_t)N * 64 * 4;   // x1
    float* dco   = (float*)p;           p += (size_t)N * 4;
    float* ga0   = (float*)p;           p += (size_t)N * 4;
    float* gb0   = (float*)p;           p += (size_t)N * 4;
    float* ga1   = (float*)p;           p += (size_t)N * 4;
    float* gb1   = (float*)p;           p += (size_t)N * 4;
    int*   cnt   = (int*)p;             p += (size_t)N * 4;
    int*   rs    = (int*)p;             p += (size_t)(N + 1) * 4;
    int*   cur   = (int*)p;             p += (size_t)N * 4;
    int*   bsum  = (int*)p;             p += 1024 * 4;
    int*   esrc  = (int*)p;             p += (size_t)E * 4;
    int*   edst  = (int*)p;             p += (size_t)E * 4;
    float* ecoef = (float*)p;           p += (size_t)E * 4;
    short* wbf   = (short*)p;

    // ---- CSR build (counting sort by dst) + degree norm ----
    zero_i32<<<NB, 256, 0, stream>>>(cnt, N);
    deg_count_i<<<(E + 255) / 256, 256, 0, stream>>>(dst, cnt, E);
    deg_finalize<<<NB, 256, 0, stream>>>(cnt, dco, N);
    scan_block<<<NB, 256, 0, stream>>>(cnt, rs, bsum, N);
    scan_top<<<1, 1024, 0, stream>>>(bsum, NB);
    scan_add<<<NB, 256, 0, stream>>>(rs, bsum, cur, N, E);
    bucket_fill<<<(E + 255) / 256, 256, 0, stream>>>(src, dst, cur, esrc, edst, E);

    // ---- t1 + relu (MFMA, LDS-staged) with fused layer-0 gate dots ----
    cvt_w<<<64, 256, 0, stream>>>(t1w, wbf);
    t1_mfma<<<(N + 63) / 64, 256, 0, stream>>>(h, wbf, t1b, gw, XA, ga0, gb0, N);

    // ---- layer 0 ----
    edge_coef<<<(E + 255) / 256, 256, 0, stream>>>(esrc, edst, ga0, gb0, dco, gbia, 0, ecoef, E);
    gather4<<<(N + 3) / 4, 256, 0, stream>>>(rs, esrc, ecoef, XA, XA, XB,
                                             gw + 128, ga1, gb1, N);

    // ---- layer 1 ----
    edge_coef<<<(E + 255) / 256, 256, 0, stream>>>(esrc, edst, ga1, gb1, dco, gbia, 1, ecoef, E);
    gather4<<<(N + 3) / 4, 256, 0, stream>>>(rs, esrc, ecoef, XB, XA, XA,
                                             nullptr, nullptr, nullptr, N);

    // ---- logits + log_softmax ----
    out_logsoftmax<<<(N + 255) / 256, 256, 0, stream>>>(XA, t2w, t2b, out, N);
}